// Round 4
// baseline (10844.697 us; speedup 1.0000x reference)
//
#include <hip/hip_runtime.h>
#include <stdint.h>

#define B_ 256
#define S_ 512
#define H_ 256
#define G_ 1024
#define CHUNK 32
#define NCHUNK (S_ / CHUNK)

typedef __attribute__((ext_vector_type(8))) short bf16x8;
typedef __attribute__((ext_vector_type(4))) float f32x4;

__device__ __forceinline__ unsigned short f2bf(float f) {
    unsigned u = __builtin_bit_cast(unsigned, f);
    unsigned r = u + 0x7fffu + ((u >> 16) & 1u);
    return (unsigned short)(r >> 16);
}
__device__ __forceinline__ float bf2f(unsigned short v) {
    return __builtin_bit_cast(float, (unsigned)v << 16);
}
__device__ __forceinline__ float bfbits_lo(unsigned v) {
    return __builtin_bit_cast(float, (unsigned)(v << 16));
}
__device__ __forceinline__ float bfbits_hi(unsigned v) {
    return __builtin_bit_cast(float, v & 0xffff0000u);
}
__device__ __forceinline__ float sigmoidf_(float x) { return 1.f / (1.f + __expf(-x)); }
__device__ __forceinline__ float tanhf_(float x) { return 2.f / (1.f + __expf(-2.f * x)) - 1.f; }

// ---------------- prep: weights -> fragment-major bf16 ----------------
// Wp[nt][kk][lane][i] = W[k][n], k = kk*32 + (lane>>4)*8 + i, n = nt*16 + (lane&15)
__global__ void prep_w(const float* __restrict__ W, unsigned short* __restrict__ Wp, int NT) {
    int tid = blockIdx.x * 256 + threadIdx.x;
    int total = NT * 8 * 64;
    if (tid >= total) return;
    int l = tid & 63, kk = (tid >> 6) & 7, nt = tid >> 9;
    int n = nt * 16 + (l & 15);
    int k0 = kk * 32 + (l >> 4) * 8;
    int N = NT * 16;
    unsigned short v[8];
#pragma unroll
    for (int i = 0; i < 8; i++) v[i] = f2bf(W[(size_t)(k0 + i) * N + n]);
    uint4 o;
    o.x = (unsigned)v[0] | ((unsigned)v[1] << 16);
    o.y = (unsigned)v[2] | ((unsigned)v[3] << 16);
    o.z = (unsigned)v[4] | ((unsigned)v[5] << 16);
    o.w = (unsigned)v[6] | ((unsigned)v[7] << 16);
    *(uint4*)(Wp + (size_t)tid * 8) = o;
}

__global__ void prep_decay(const float* __restrict__ x, float* __restrict__ dec, int n) {
    int i = blockIdx.x * 256 + threadIdx.x;
    if (i < n) dec[i] = 1.f / __logf(2.718281828459045f + x[(size_t)i * H_ + (H_ - 1)]);
}

// ---------------- xg GEMM body (unchanged structure) ----------------
template <bool SRCF32>
__device__ void gemm_body(const void* __restrict__ src, const unsigned short* __restrict__ Wp,
                          const float* __restrict__ bias, unsigned short* __restrict__ xgp,
                          int chunk, short* Albs) {
    const int tid = threadIdx.x;
    const int bx = blockIdx.x;  // 0..63 M-tile (128 rows)
    const int by = blockIdx.y;  // 0..7  N-block
    const int r0 = bx * 128;
    const int t_loc = r0 >> 8;
    const int b0 = r0 & 255;
    const int sg = chunk * CHUNK + t_loc;
    {
        const int m = tid >> 1, kh = tid & 1;
        const size_t rowbase = ((size_t)(b0 + m) * S_ + sg) * H_ + kh * 128;
        if constexpr (SRCF32) {
            const float* p = (const float*)src + rowbase;
#pragma unroll
            for (int jo = 0; jo < 16; jo++) {
                int k = kh * 128 + jo * 8;
                float4 a = *(const float4*)(p + jo * 8);
                float4 b = *(const float4*)(p + jo * 8 + 4);
                int slot = ((m >> 4) * 8 + (k >> 5)) * 64 + ((m & 15) | (((k >> 3) & 3) << 4));
                uint4 o;
                o.x = (unsigned)f2bf(a.x) | ((unsigned)f2bf(a.y) << 16);
                o.y = (unsigned)f2bf(a.z) | ((unsigned)f2bf(a.w) << 16);
                o.z = (unsigned)f2bf(b.x) | ((unsigned)f2bf(b.y) << 16);
                o.w = (unsigned)f2bf(b.z) | ((unsigned)f2bf(b.w) << 16);
                *(uint4*)&Albs[slot * 8] = o;
            }
        } else {
            const unsigned short* p = (const unsigned short*)src + rowbase;
#pragma unroll
            for (int jo = 0; jo < 16; jo++) {
                int k = kh * 128 + jo * 8;
                uint4 o = *(const uint4*)(p + jo * 8);
                int slot = ((m >> 4) * 8 + (k >> 5)) * 64 + ((m & 15) | (((k >> 3) & 3) << 4));
                *(uint4*)&Albs[slot * 8] = o;
            }
        }
    }
    __syncthreads();
    const int w = tid >> 6, l = tid & 63;
    const int wm = w >> 1, wn = w & 1;
    const int col = l & 15;
    float bv[4];
#pragma unroll
    for (int q = 0; q < 4; q++) bv[q] = bias[(by * 8 + wn * 4 + q) * 16 + col];
    f32x4 acc[4][4];
#pragma unroll
    for (int mi = 0; mi < 4; mi++)
#pragma unroll
        for (int q = 0; q < 4; q++) {
            acc[mi][q][0] = bv[q]; acc[mi][q][1] = bv[q];
            acc[mi][q][2] = bv[q]; acc[mi][q][3] = bv[q];
        }
    const bf16x8* Wp8 = (const bf16x8*)Wp;
#pragma unroll
    for (int kk = 0; kk < 8; kk++) {
        bf16x8 af[4], bfr[4];
#pragma unroll
        for (int mi = 0; mi < 4; mi++)
            af[mi] = *(const bf16x8*)&Albs[(((wm * 4 + mi) * 8 + kk) * 64 + l) * 8];
#pragma unroll
        for (int q = 0; q < 4; q++)
            bfr[q] = Wp8[((size_t)(by * 8 + wn * 4 + q) * 8 + kk) * 64 + l];
#pragma unroll
        for (int mi = 0; mi < 4; mi++)
#pragma unroll
            for (int q = 0; q < 4; q++)
                acc[mi][q] = __builtin_amdgcn_mfma_f32_16x16x32_bf16(af[mi], bfr[q], acc[mi][q], 0, 0, 0);
    }
    const int rblk0 = r0 >> 4;
#pragma unroll
    for (int mi = 0; mi < 4; mi++) {
        int rowblk = rblk0 + wm * 4 + mi;
#pragma unroll
        for (int q = 0; q < 4; q++) {
            int qg = by * 8 + wn * 4 + q;
            uint2 o;
            o.x = (unsigned)f2bf(acc[mi][q][0]) | ((unsigned)f2bf(acc[mi][q][1]) << 16);
            o.y = (unsigned)f2bf(acc[mi][q][2]) | ((unsigned)f2bf(acc[mi][q][3]) << 16);
            *(uint2*)&xgp[(((size_t)rowblk * 64 + qg) * 64 + l) * 4] = o;
        }
    }
}

__global__ __launch_bounds__(256) void gemm_dual(const float* __restrict__ x,
                                                 const unsigned short* __restrict__ y0bf,
                                                 const unsigned short* __restrict__ Wp0,
                                                 const float* __restrict__ bias0,
                                                 const unsigned short* __restrict__ Wp1,
                                                 const float* __restrict__ bias1,
                                                 unsigned short* __restrict__ xgpA,
                                                 unsigned short* __restrict__ xgpB, int c0, int c1) {
    extern __shared__ short Albs[];  // 64 KB
    if (blockIdx.z == 0) {
        if (c0 < 0) return;
        gemm_body<true>(x, Wp0, bias0, xgpA, c0, Albs);
    } else {
        if (c1 < 0) return;
        gemm_body<false>(y0bf, Wp1, bias1, xgpB, c1, Albs);
    }
}

// ---------------- recurrent scan: register-resident weights, 2-WG groups ----------------
// Group = (layer, bblk). 2 WGs/group, each 512 thr (8 waves), owns 128 output cols.
// Wave w owns col-tile ct = half*8 + w: Wh tiles {q*16+ct} (128 VGPR) + Wd tile ct (32 VGPR),
// loaded ONCE per chunk. Per step: MFMA from registers + LDS h/c, elementwise, then 8 KB
// half-exchange with partner WG via device-scope atomics (epoch flags, parity buffers).
template <bool ISL0>
__device__ void rec_run(const unsigned short* __restrict__ xgp, const bf16x8* __restrict__ Whp8,
                        const bf16x8* __restrict__ Wdp8, const float* __restrict__ bd,
                        const float* __restrict__ dec_in, void* __restrict__ yout,
                        float* __restrict__ dec_out, unsigned short* __restrict__ h_state,
                        float* __restrict__ c_state, unsigned* __restrict__ xch,
                        unsigned* __restrict__ flags, int chunk, int g, int half, int bblk,
                        char* smem) {
    short* hb = (short*)smem;                     // [2][16][256]
    short* cbuf = (short*)(smem + 2 * 4096 * 2);  // [2][16][256]
    float* decs = (float*)(smem + 4 * 4096 * 2);  // [CHUNK][17]
    const int tid = threadIdx.x;  // 0..511
    const int w = tid >> 6, l = tid & 63;
    const int lgrp = l >> 4, col = l & 15;
    const int b0 = bblk * 16;
    const int ct = half * 8 + w;         // col-tile 0..15
    const int n = ct * 16 + col;         // output column
    const float bdv = bd[n];

    {  // stage decay for this chunk
        int row = tid >> 5, t = tid & (CHUNK - 1);
        decs[t * 17 + row] = dec_in[(size_t)(b0 + row) * S_ + chunk * CHUNK + t];
    }
    // chunk-resident weights
    bf16x8 wd[8], wh[4][8];
#pragma unroll
    for (int kk = 0; kk < 8; kk++) wd[kk] = Wdp8[((size_t)ct * 8 + kk) * 64 + l];
#pragma unroll
    for (int q = 0; q < 4; q++)
#pragma unroll
        for (int kk = 0; kk < 8; kk++)
            wh[q][kk] = Whp8[((size_t)(q * 16 + ct) * 8 + kk) * 64 + l];

    float creg[4];
    if (chunk == 0) {
#pragma unroll
        for (int r = 0; r < 4; r++) creg[r] = 0.f;
        for (int i = tid; i < 4096; i += 512) { hb[i] = 0; cbuf[i] = 0; }
    } else {
        // stage FULL h,c (both halves) from global state into parity-0 buffers
        for (int i = 0; i < 8; i++) {
            int idx = tid + i * 512;
            int row = idx >> 8, nn = idx & 255;
            unsigned short hv = h_state[(size_t)(b0 + row) * H_ + nn];
            float cv = c_state[(size_t)(b0 + row) * H_ + nn];
            int sw = nn ^ ((row & 7) << 3);
            hb[row * 256 + sw] = (short)hv;
            cbuf[row * 256 + sw] = (short)f2bf(cv);
        }
#pragma unroll
        for (int r = 0; r < 4; r++)
            creg[r] = c_state[(size_t)(b0 + lgrp * 4 + r) * H_ + n];
    }
    __syncthreads();

    const uint2* xg8 = (const uint2*)xgp;
    uint2 xc[4], xn[4];
#pragma unroll
    for (int q = 0; q < 4; q++)
        xc[q] = xg8[((size_t)(0 * 16 + bblk) * 64 + (q * 16 + ct)) * 64 + l];
    int cur = 0;
    bool alive = true;
    unsigned* myflag = &flags[(g * 2 + half) * 32];
    unsigned* pflag = &flags[(g * 2 + (1 - half)) * 32];

#pragma unroll 1
    for (int t = 0; t < CHUNK; ++t) {
        const int tg = chunk * CHUNK + t;
        if (t + 1 < CHUNK) {  // prefetch next step's xg
            int rb = (t + 1) * 16 + bblk;
#pragma unroll
            for (int q = 0; q < 4; q++)
                xn[q] = xg8[((size_t)rb * 64 + (q * 16 + ct)) * 64 + l];
        }
        const short* hc = hb + cur * 4096;
        const short* cc = cbuf + cur * 4096;
        f32x4 csacc = {0.f, 0.f, 0.f, 0.f};
        f32x4 gacc[4];
#pragma unroll
        for (int q = 0; q < 4; q++) {
            uint2 v = xc[q];
            gacc[q][0] = bfbits_lo(v.x);
            gacc[q][1] = bfbits_hi(v.x);
            gacc[q][2] = bfbits_lo(v.y);
            gacc[q][3] = bfbits_hi(v.y);
        }
#pragma unroll
        for (int kk = 0; kk < 8; kk++) {
            bf16x8 hf = *(const bf16x8*)&hc[col * 256 + ((kk * 32 + lgrp * 8) ^ ((col & 7) << 3))];
            bf16x8 cf = *(const bf16x8*)&cc[col * 256 + ((kk * 32 + lgrp * 8) ^ ((col & 7) << 3))];
            csacc = __builtin_amdgcn_mfma_f32_16x16x32_bf16(cf, wd[kk], csacc, 0, 0, 0);
#pragma unroll
            for (int q = 0; q < 4; q++)
                gacc[q] = __builtin_amdgcn_mfma_f32_16x16x32_bf16(hf, wh[q][kk], gacc[q], 0, 0, 0);
        }
        short* hx = hb + (cur ^ 1) * 4096;
        short* cx = cbuf + (cur ^ 1) * 4096;
        unsigned* xout = xch + (((size_t)(g * 2 + half)) * 2 + (cur ^ 1)) * 2048;
#pragma unroll
        for (int r = 0; r < 4; r++) {
            int row = lgrp * 4 + r;
            float dec = decs[t * 17 + row];
            float cs = tanhf_(csacc[r] + bdv);
            float cadj = creg[r] - cs + cs * dec;
            float iv = sigmoidf_(gacc[0][r]);
            float fv = sigmoidf_(gacc[1][r]);
            float ov = sigmoidf_(gacc[2][r]);
            float cd = tanhf_(gacc[3][r]);
            float cn = fv * cadj + iv * cd;
            float hn = ov * tanhf_(cn);
            creg[r] = cn;
            int sw = n ^ ((row & 7) << 3);
            unsigned hnb = f2bf(hn), cnb = f2bf(cn);
            hx[row * 256 + sw] = (short)hnb;
            cx[row * 256 + sw] = (short)cnb;
            if (t + 1 < CHUNK)
                __hip_atomic_store(&xout[row * 128 + w * 16 + col], hnb | (cnb << 16),
                                   __ATOMIC_RELAXED, __HIP_MEMORY_SCOPE_AGENT);
            size_t yi = ((size_t)(b0 + row) * S_ + tg) * H_ + n;
            if constexpr (ISL0) {
                ((unsigned short*)yout)[yi] = (unsigned short)hnb;
                if (half == 1 && w == 7 && col == 15)
                    dec_out[(size_t)(b0 + row) * S_ + tg] =
                        1.f / __logf(2.718281828459045f + hn);
            } else {
                ((float*)yout)[yi] = hn;
            }
            if (t == CHUNK - 1) {
                h_state[(size_t)(b0 + row) * H_ + n] = (unsigned short)hnb;
                c_state[(size_t)(b0 + row) * H_ + n] = cn;
            }
        }
        if (t + 1 < CHUNK) {
            const unsigned ep = (unsigned)(chunk * CHUNK + t + 1);
            __threadfence();
            __syncthreads();
            if (tid == 0)
                __hip_atomic_store(myflag, ep, __ATOMIC_RELEASE, __HIP_MEMORY_SCOPE_AGENT);
            if (alive) {
                int spins = 0;
                while (__hip_atomic_load(pflag, __ATOMIC_ACQUIRE, __HIP_MEMORY_SCOPE_AGENT) < ep) {
                    __builtin_amdgcn_s_sleep(2);
                    if (++spins > 20000000) { alive = false; break; }
                }
            }
            unsigned* xin = xch + (((size_t)(g * 2 + (1 - half))) * 2 + (cur ^ 1)) * 2048;
#pragma unroll
            for (int i = 0; i < 4; i++) {
                int j = tid + i * 512;
                unsigned v = __hip_atomic_load(&xin[j], __ATOMIC_RELAXED, __HIP_MEMORY_SCOPE_AGENT);
                int row = j >> 7, cl = j & 127;
                int n2 = (1 - half) * 128 + cl;
                int sw2 = n2 ^ ((row & 7) << 3);
                hx[row * 256 + sw2] = (short)(v & 0xffffu);
                cx[row * 256 + sw2] = (short)(v >> 16);
            }
            __syncthreads();
        }
#pragma unroll
        for (int q = 0; q < 4; q++) xc[q] = xn[q];
        cur ^= 1;
    }
}

// 64 WGs: blockIdx b -> group g = ((b>>4)<<3)|(b&7), half=(b>>3)&1 (partners share b%8 -> same XCD)
__global__ __launch_bounds__(512, 2) void rec_fused(
    const unsigned short* __restrict__ xgpA, const unsigned short* __restrict__ Whp0,
    const unsigned short* __restrict__ Wdp0, const float* __restrict__ bd0,
    const float* __restrict__ dec0, unsigned short* __restrict__ y0bf,
    float* __restrict__ dec1, unsigned short* __restrict__ hs0, float* __restrict__ cs0,
    const unsigned short* __restrict__ xgpB, const unsigned short* __restrict__ Whp1,
    const unsigned short* __restrict__ Wdp1, const float* __restrict__ bd1,
    float* __restrict__ y1, unsigned short* __restrict__ hs1, float* __restrict__ cs1,
    unsigned* __restrict__ xch, unsigned* __restrict__ flags, int c0, int c1) {
    extern __shared__ char smem[];
    int b = blockIdx.x;
    int g = ((b >> 4) << 3) | (b & 7);
    int half = (b >> 3) & 1;
    int layer = g >> 4, bblk = g & 15;
    if (layer == 0) {
        if (c0 < 0) return;
        rec_run<true>(xgpA, (const bf16x8*)Whp0, (const bf16x8*)Wdp0, bd0, dec0, y0bf, dec1,
                      hs0, cs0, xch, flags, c0, g, half, bblk, smem);
    } else {
        if (c1 < 0) return;
        rec_run<false>(xgpB, (const bf16x8*)Whp1, (const bf16x8*)Wdp1, bd1, dec1, y1, nullptr,
                       hs1, cs1, xch, flags, c1, g, half, bblk, smem);
    }
}

__global__ void copy_tail(const unsigned short* __restrict__ h0, const float* __restrict__ c0,
                          const unsigned short* __restrict__ h1, const float* __restrict__ c1,
                          float* __restrict__ out) {
    int i = blockIdx.x * 256 + threadIdx.x;
    if (i >= 4 * 65536) return;
    int which = i >> 16, j = i & 65535;
    float v = which == 0 ? bf2f(h0[j]) : which == 1 ? c0[j] : which == 2 ? bf2f(h1[j]) : c1[j];
    out[i] = v;
}

extern "C" void kernel_launch(void* const* d_in, const int* in_sizes, int n_in, void* d_out,
                              int out_size, void* d_ws, size_t ws_size, hipStream_t stream) {
    (void)in_sizes; (void)n_in; (void)out_size; (void)ws_size;
    const float* x   = (const float*)d_in[0];
    const float* Wx0 = (const float*)d_in[1];
    const float* Wh0 = (const float*)d_in[2];
    const float* b0  = (const float*)d_in[3];
    const float* Wd0 = (const float*)d_in[4];
    const float* bd0 = (const float*)d_in[5];
    const float* Wx1 = (const float*)d_in[6];
    const float* Wh1 = (const float*)d_in[7];
    const float* b1  = (const float*)d_in[8];
    const float* Wd1 = (const float*)d_in[9];
    const float* bd1 = (const float*)d_in[10];

    char* ws = (char*)d_ws;
    size_t off = 0;
    auto take = [&](size_t bytes) { void* p = ws + off; off += (bytes + 255) & ~(size_t)255; return p; };
    unsigned short* wxp0 = (unsigned short*)take(524288);
    unsigned short* whp0 = (unsigned short*)take(524288);
    unsigned short* wdp0 = (unsigned short*)take(131072);
    unsigned short* wxp1 = (unsigned short*)take(524288);
    unsigned short* whp1 = (unsigned short*)take(524288);
    unsigned short* wdp1 = (unsigned short*)take(131072);
    float* dec0 = (float*)take(524288);
    float* dec1 = (float*)take(524288);
    unsigned short* hs0 = (unsigned short*)take(131072);
    float* cs0 = (float*)take(262144);
    unsigned short* hs1 = (unsigned short*)take(131072);
    float* cs1 = (float*)take(262144);
    unsigned short* y0bf = (unsigned short*)take(67108864);
    unsigned short* xgpA = (unsigned short*)take(16777216);
    unsigned short* xgpB = (unsigned short*)take(16777216);
    unsigned* xch   = (unsigned*)take(64 * 2 * 2048 * 4);  // 1 MB exchange
    unsigned* flags = (unsigned*)take(64 * 32 * 4);        // 8 KB flags

    hipMemsetAsync(flags, 0, 64 * 32 * 4, stream);

    prep_w<<<128, 256, 0, stream>>>(Wx0, wxp0, 64);
    prep_w<<<128, 256, 0, stream>>>(Wh0, whp0, 64);
    prep_w<<<32, 256, 0, stream>>>(Wd0, wdp0, 16);
    prep_w<<<128, 256, 0, stream>>>(Wx1, wxp1, 64);
    prep_w<<<128, 256, 0, stream>>>(Wh1, whp1, 64);
    prep_w<<<32, 256, 0, stream>>>(Wd1, wdp1, 16);
    prep_decay<<<512, 256, 0, stream>>>(x, dec0, B_ * S_);

    float* y1 = (float*)d_out;
    const size_t smem_rec = 4 * 4096 * 2 + CHUNK * 17 * 4;  // 34.9 KB
    for (int s = 0; s <= NCHUNK; ++s) {
        int c0 = (s < NCHUNK) ? s : -1;
        int c1 = (s >= 1) ? s - 1 : -1;
        gemm_dual<<<dim3(64, 8, 2), 256, 65536, stream>>>(x, y0bf, wxp0, b0, wxp1, b1,
                                                          xgpA, xgpB, c0, c1);
        rec_fused<<<64, 512, smem_rec, stream>>>(xgpA, whp0, wdp0, bd0, dec0, y0bf, dec1,
                                                 hs0, cs0, xgpB, whp1, wdp1, bd1, y1,
                                                 hs1, cs1, xch, flags, c0, c1);
    }
    copy_tail<<<1024, 256, 0, stream>>>(hs0, cs0, hs1, cs1, y1 + (size_t)B_ * S_ * H_);
}

// Round 5
// 8793.214 us; speedup vs baseline: 1.2333x; 1.2333x over previous
//
#include <hip/hip_runtime.h>
#include <stdint.h>

#define B_ 256
#define S_ 512
#define H_ 256
#define G_ 1024
#define CHUNK 32
#define NCHUNK (S_ / CHUNK)

typedef __attribute__((ext_vector_type(8))) short bf16x8;
typedef __attribute__((ext_vector_type(4))) float f32x4;

__device__ __forceinline__ unsigned short f2bf(float f) {
    unsigned u = __builtin_bit_cast(unsigned, f);
    unsigned r = u + 0x7fffu + ((u >> 16) & 1u);
    return (unsigned short)(r >> 16);
}
__device__ __forceinline__ float bf2f(unsigned short v) {
    return __builtin_bit_cast(float, (unsigned)v << 16);
}
__device__ __forceinline__ float bfbits_lo(unsigned v) {
    return __builtin_bit_cast(float, (unsigned)(v << 16));
}
__device__ __forceinline__ float bfbits_hi(unsigned v) {
    return __builtin_bit_cast(float, v & 0xffff0000u);
}
__device__ __forceinline__ float sigmoidf_(float x) { return 1.f / (1.f + __expf(-x)); }
__device__ __forceinline__ float tanhf_(float x) { return 2.f / (1.f + __expf(-2.f * x)) - 1.f; }

// async global->LDS, 16B per lane; LDS dest must be wave-uniform base (lane*16 implicit)
__device__ __forceinline__ void gload_lds16(const void* g, void* s) {
    __builtin_amdgcn_global_load_lds((const __attribute__((address_space(1))) unsigned int*)g,
                                     (__attribute__((address_space(3))) unsigned int*)s, 16, 0, 0);
}

// ---------------- prep: weights -> fragment-major bf16 ----------------
// Wp[nt][kk][lane][i] = W[k][n], k = kk*32 + (lane>>4)*8 + i, n = nt*16 + (lane&15)
__global__ void prep_w(const float* __restrict__ W, unsigned short* __restrict__ Wp, int NT) {
    int tid = blockIdx.x * 256 + threadIdx.x;
    int total = NT * 8 * 64;
    if (tid >= total) return;
    int l = tid & 63, kk = (tid >> 6) & 7, nt = tid >> 9;
    int n = nt * 16 + (l & 15);
    int k0 = kk * 32 + (l >> 4) * 8;
    int N = NT * 16;
    unsigned short v[8];
#pragma unroll
    for (int i = 0; i < 8; i++) v[i] = f2bf(W[(size_t)(k0 + i) * N + n]);
    uint4 o;
    o.x = (unsigned)v[0] | ((unsigned)v[1] << 16);
    o.y = (unsigned)v[2] | ((unsigned)v[3] << 16);
    o.z = (unsigned)v[4] | ((unsigned)v[5] << 16);
    o.w = (unsigned)v[6] | ((unsigned)v[7] << 16);
    *(uint4*)(Wp + (size_t)tid * 8) = o;
}

__global__ void prep_decay(const float* __restrict__ x, float* __restrict__ dec, int n) {
    int i = blockIdx.x * 256 + threadIdx.x;
    if (i < n) dec[i] = 1.f / __logf(2.718281828459045f + x[(size_t)i * H_ + (H_ - 1)]);
}

// ---------------- xg GEMM body (unchanged) ----------------
template <bool SRCF32>
__device__ void gemm_body(const void* __restrict__ src, const unsigned short* __restrict__ Wp,
                          const float* __restrict__ bias, unsigned short* __restrict__ xgp,
                          int chunk, short* Albs) {
    const int tid = threadIdx.x;
    const int bx = blockIdx.x;  // 0..63 M-tile (128 rows)
    const int by = blockIdx.y;  // 0..7  N-block
    const int r0 = bx * 128;
    const int t_loc = r0 >> 8;
    const int b0 = r0 & 255;
    const int sg = chunk * CHUNK + t_loc;
    {
        const int m = tid >> 1, kh = tid & 1;
        const size_t rowbase = ((size_t)(b0 + m) * S_ + sg) * H_ + kh * 128;
        if constexpr (SRCF32) {
            const float* p = (const float*)src + rowbase;
#pragma unroll
            for (int jo = 0; jo < 16; jo++) {
                int k = kh * 128 + jo * 8;
                float4 a = *(const float4*)(p + jo * 8);
                float4 b = *(const float4*)(p + jo * 8 + 4);
                int slot = ((m >> 4) * 8 + (k >> 5)) * 64 + ((m & 15) | (((k >> 3) & 3) << 4));
                uint4 o;
                o.x = (unsigned)f2bf(a.x) | ((unsigned)f2bf(a.y) << 16);
                o.y = (unsigned)f2bf(a.z) | ((unsigned)f2bf(a.w) << 16);
                o.z = (unsigned)f2bf(b.x) | ((unsigned)f2bf(b.y) << 16);
                o.w = (unsigned)f2bf(b.z) | ((unsigned)f2bf(b.w) << 16);
                *(uint4*)&Albs[slot * 8] = o;
            }
        } else {
            const unsigned short* p = (const unsigned short*)src + rowbase;
#pragma unroll
            for (int jo = 0; jo < 16; jo++) {
                int k = kh * 128 + jo * 8;
                uint4 o = *(const uint4*)(p + jo * 8);
                int slot = ((m >> 4) * 8 + (k >> 5)) * 64 + ((m & 15) | (((k >> 3) & 3) << 4));
                *(uint4*)&Albs[slot * 8] = o;
            }
        }
    }
    __syncthreads();
    const int w = tid >> 6, l = tid & 63;
    const int wm = w >> 1, wn = w & 1;
    const int col = l & 15;
    float bv[4];
#pragma unroll
    for (int q = 0; q < 4; q++) bv[q] = bias[(by * 8 + wn * 4 + q) * 16 + col];
    f32x4 acc[4][4];
#pragma unroll
    for (int mi = 0; mi < 4; mi++)
#pragma unroll
        for (int q = 0; q < 4; q++) {
            acc[mi][q][0] = bv[q]; acc[mi][q][1] = bv[q];
            acc[mi][q][2] = bv[q]; acc[mi][q][3] = bv[q];
        }
    const bf16x8* Wp8 = (const bf16x8*)Wp;
#pragma unroll
    for (int kk = 0; kk < 8; kk++) {
        bf16x8 af[4], bfr[4];
#pragma unroll
        for (int mi = 0; mi < 4; mi++)
            af[mi] = *(const bf16x8*)&Albs[(((wm * 4 + mi) * 8 + kk) * 64 + l) * 8];
#pragma unroll
        for (int q = 0; q < 4; q++)
            bfr[q] = Wp8[((size_t)(by * 8 + wn * 4 + q) * 8 + kk) * 64 + l];
#pragma unroll
        for (int mi = 0; mi < 4; mi++)
#pragma unroll
            for (int q = 0; q < 4; q++)
                acc[mi][q] = __builtin_amdgcn_mfma_f32_16x16x32_bf16(af[mi], bfr[q], acc[mi][q], 0, 0, 0);
    }
    const int rblk0 = r0 >> 4;
#pragma unroll
    for (int mi = 0; mi < 4; mi++) {
        int rowblk = rblk0 + wm * 4 + mi;
#pragma unroll
        for (int q = 0; q < 4; q++) {
            int qg = by * 8 + wn * 4 + q;
            uint2 o;
            o.x = (unsigned)f2bf(acc[mi][q][0]) | ((unsigned)f2bf(acc[mi][q][1]) << 16);
            o.y = (unsigned)f2bf(acc[mi][q][2]) | ((unsigned)f2bf(acc[mi][q][3]) << 16);
            *(uint2*)&xgp[(((size_t)rowblk * 64 + qg) * 64 + l) * 4] = o;
        }
    }
}

__global__ __launch_bounds__(256) void gemm_dual(const float* __restrict__ x,
                                                 const unsigned short* __restrict__ y0bf,
                                                 const unsigned short* __restrict__ Wp0,
                                                 const float* __restrict__ bias0,
                                                 const unsigned short* __restrict__ Wp1,
                                                 const float* __restrict__ bias1,
                                                 unsigned short* __restrict__ xgpA,
                                                 unsigned short* __restrict__ xgpB, int c0, int c1) {
    extern __shared__ short Albs[];  // 64 KB
    if (blockIdx.z == 0) {
        if (c0 < 0) return;
        gemm_body<true>(x, Wp0, bias0, xgpA, c0, Albs);
    } else {
        if (c1 < 0) return;
        gemm_body<false>(y0bf, Wp1, bias1, xgpB, c1, Albs);
    }
}

// ---------------- recurrent scan: LDS-DMA weight streaming ----------------
// 32 WGs (16/layer), 1024 thr (16 waves). Wave w owns col-tile w (16 cols): 4 gate tiles
// streamed per kk via global_load_lds into a parity dbuf (no VGPR pressure), Wd tile
// register-resident. h/c single LDS copy, 2 barriers/step.
template <bool ISL0>
__device__ void rec_run(const unsigned short* __restrict__ xgp, const bf16x8* __restrict__ Whp8,
                        const bf16x8* __restrict__ Wdp8, const float* __restrict__ bd,
                        const float* __restrict__ dec_in, void* __restrict__ yout,
                        float* __restrict__ dec_out, unsigned short* __restrict__ h_state,
                        float* __restrict__ c_state, int chunk, int bblk, char* smem) {
    short* stage = (short*)smem;           // [2][16 waves][4 frags * 512 shorts] = 128 KB
    short* hb = (short*)(smem + 131072);   // [16][256] bf16
    short* cb = (short*)(smem + 139264);   // [16][256] bf16
    const int tid = threadIdx.x;           // 0..1023
    const int w = tid >> 6, l = tid & 63;
    const int lgrp = l >> 4, col = l & 15;
    const int b0 = bblk * 16;
    const int n = w * 16 + col;
    const float bdv = bd[n];

    // Wd tile w resident in registers (32 VGPR)
    bf16x8 wd[8];
#pragma unroll
    for (int kk = 0; kk < 8; kk++) wd[kk] = Wdp8[((size_t)w * 8 + kk) * 64 + l];

    float creg[4];
    if (chunk == 0) {
#pragma unroll
        for (int r = 0; r < 4; r++) creg[r] = 0.f;
        for (int i = tid; i < 4096; i += 1024) { hb[i] = 0; cb[i] = 0; }
    } else {
#pragma unroll
        for (int i = 0; i < 4; i++) {
            int idx = tid + i * 1024;
            int row = idx >> 8, nn = idx & 255;
            int sw = nn ^ ((row & 7) << 3);
            hb[row * 256 + sw] = (short)h_state[(size_t)(b0 + row) * H_ + nn];
            cb[row * 256 + sw] = (short)f2bf(c_state[(size_t)(b0 + row) * H_ + nn]);
        }
#pragma unroll
        for (int r = 0; r < 4; r++)
            creg[r] = c_state[(size_t)(b0 + lgrp * 4 + r) * H_ + n];
    }
    const uint2* xg8 = (const uint2*)xgp;
    uint2 xc[4], xn[4];
#pragma unroll
    for (int q = 0; q < 4; q++)
        xc[q] = xg8[((size_t)bblk * 64 + (q * 16 + w)) * 64 + l];
    __syncthreads();

    short* swave0 = stage + ((size_t)w) * 2048;           // parity-0 region for this wave
    short* swave1 = stage + ((size_t)(16 + w)) * 2048;    // parity-1 region
    // prologue: issue kk=0 batch into parity 0
#pragma unroll
    for (int q = 0; q < 4; q++)
        gload_lds16(Whp8 + ((size_t)(q * 16 + w) * 8 + 0) * 64 + l, swave0 + q * 512);

#pragma unroll 1
    for (int t = 0; t < CHUNK; ++t) {
        const int tg = chunk * CHUNK + t;
        float dcur[4];
#pragma unroll
        for (int r = 0; r < 4; r++)
            dcur[r] = dec_in[(size_t)(b0 + lgrp * 4 + r) * S_ + tg];
        if (t + 1 < CHUNK) {  // prefetch next step's xg into regs
            int rb = (t + 1) * 16 + bblk;
#pragma unroll
            for (int q = 0; q < 4; q++)
                xn[q] = xg8[((size_t)rb * 64 + (q * 16 + w)) * 64 + l];
        }
        f32x4 csacc = {0.f, 0.f, 0.f, 0.f};
        f32x4 gacc[4];
#pragma unroll
        for (int q = 0; q < 4; q++) {
            uint2 v = xc[q];
            gacc[q][0] = bfbits_lo(v.x);
            gacc[q][1] = bfbits_hi(v.x);
            gacc[q][2] = bfbits_lo(v.y);
            gacc[q][3] = bfbits_hi(v.y);
        }
#pragma unroll
        for (int kk = 0; kk < 8; kk++) {
            __builtin_amdgcn_s_waitcnt(0x0F70);  // vmcnt(0): current batch arrived in LDS
            __builtin_amdgcn_sched_barrier(0);
            const short* sbuf = (kk & 1) ? swave1 : swave0;
            const int ha = col * 256 + ((kk * 32 + lgrp * 8) ^ ((col & 7) << 3));
            bf16x8 hf = *(const bf16x8*)&hb[ha];
            bf16x8 cf = *(const bf16x8*)&cb[ha];
            csacc = __builtin_amdgcn_mfma_f32_16x16x32_bf16(cf, wd[kk], csacc, 0, 0, 0);
#pragma unroll
            for (int q = 0; q < 4; q++) {
                bf16x8 wf = *(const bf16x8*)&sbuf[q * 512 + l * 8];
                gacc[q] = __builtin_amdgcn_mfma_f32_16x16x32_bf16(hf, wf, gacc[q], 0, 0, 0);
            }
            // issue next batch (kk+1; kk==7 issues next step's kk0 into parity 0)
            const int kn = (kk + 1) & 7;
            short* sdst = ((kk + 1) & 1) ? swave1 : swave0;
#pragma unroll
            for (int q = 0; q < 4; q++)
                gload_lds16(Whp8 + ((size_t)(q * 16 + w) * 8 + kn) * 64 + l, sdst + q * 512);
        }
        __syncthreads();  // all hb/cb reads of this step done
#pragma unroll
        for (int r = 0; r < 4; r++) {
            int row = lgrp * 4 + r;
            float cs = tanhf_(csacc[r] + bdv);
            float cadj = creg[r] - cs + cs * dcur[r];
            float iv = sigmoidf_(gacc[0][r]);
            float fv = sigmoidf_(gacc[1][r]);
            float ov = sigmoidf_(gacc[2][r]);
            float cd = tanhf_(gacc[3][r]);
            float cn = fv * cadj + iv * cd;
            float hn = ov * tanhf_(cn);
            creg[r] = cn;
            int sw = n ^ ((row & 7) << 3);
            unsigned short hnb = f2bf(hn);
            hb[row * 256 + sw] = (short)hnb;
            cb[row * 256 + sw] = (short)f2bf(cn);
            size_t yi = ((size_t)(b0 + row) * S_ + tg) * H_ + n;
            if constexpr (ISL0) {
                ((unsigned short*)yout)[yi] = hnb;
                if (w == 15 && col == 15)
                    dec_out[(size_t)(b0 + row) * S_ + tg] = 1.f / __logf(2.718281828459045f + hn);
            } else {
                ((float*)yout)[yi] = hn;
            }
            if (t == CHUNK - 1) {
                h_state[(size_t)(b0 + row) * H_ + n] = hnb;
                c_state[(size_t)(b0 + row) * H_ + n] = cn;
            }
        }
        __syncthreads();  // new hb/cb visible
#pragma unroll
        for (int q = 0; q < 4; q++) xc[q] = xn[q];
    }
}

// 32 WGs: blocks 0..15 -> layer0 chunk c0, 16..31 -> layer1 chunk c1
__global__ __launch_bounds__(1024, 4) void rec_fused(
    const unsigned short* __restrict__ xgpA, const unsigned short* __restrict__ Whp0,
    const unsigned short* __restrict__ Wdp0, const float* __restrict__ bd0,
    const float* __restrict__ dec0, unsigned short* __restrict__ y0bf,
    float* __restrict__ dec1, unsigned short* __restrict__ hs0, float* __restrict__ cs0,
    const unsigned short* __restrict__ xgpB, const unsigned short* __restrict__ Whp1,
    const unsigned short* __restrict__ Wdp1, const float* __restrict__ bd1,
    float* __restrict__ y1, unsigned short* __restrict__ hs1, float* __restrict__ cs1,
    int c0, int c1) {
    extern __shared__ char smem[];
    int lay = blockIdx.x >> 4, bblk = blockIdx.x & 15;
    if (lay == 0) {
        if (c0 < 0) return;
        rec_run<true>(xgpA, (const bf16x8*)Whp0, (const bf16x8*)Wdp0, bd0, dec0, y0bf, dec1,
                      hs0, cs0, c0, bblk, smem);
    } else {
        if (c1 < 0) return;
        rec_run<false>(xgpB, (const bf16x8*)Whp1, (const bf16x8*)Wdp1, bd1, dec1, y1, nullptr,
                       hs1, cs1, c1, bblk, smem);
    }
}

__global__ void copy_tail(const unsigned short* __restrict__ h0, const float* __restrict__ c0,
                          const unsigned short* __restrict__ h1, const float* __restrict__ c1,
                          float* __restrict__ out) {
    int i = blockIdx.x * 256 + threadIdx.x;
    if (i >= 4 * 65536) return;
    int which = i >> 16, j = i & 65535;
    float v = which == 0 ? bf2f(h0[j]) : which == 1 ? c0[j] : which == 2 ? bf2f(h1[j]) : c1[j];
    out[i] = v;
}

extern "C" void kernel_launch(void* const* d_in, const int* in_sizes, int n_in, void* d_out,
                              int out_size, void* d_ws, size_t ws_size, hipStream_t stream) {
    (void)in_sizes; (void)n_in; (void)out_size; (void)ws_size;
    const float* x   = (const float*)d_in[0];
    const float* Wx0 = (const float*)d_in[1];
    const float* Wh0 = (const float*)d_in[2];
    const float* b0  = (const float*)d_in[3];
    const float* Wd0 = (const float*)d_in[4];
    const float* bd0 = (const float*)d_in[5];
    const float* Wx1 = (const float*)d_in[6];
    const float* Wh1 = (const float*)d_in[7];
    const float* b1  = (const float*)d_in[8];
    const float* Wd1 = (const float*)d_in[9];
    const float* bd1 = (const float*)d_in[10];

    char* ws = (char*)d_ws;
    size_t off = 0;
    auto take = [&](size_t bytes) { void* p = ws + off; off += (bytes + 255) & ~(size_t)255; return p; };
    unsigned short* wxp0 = (unsigned short*)take(524288);
    unsigned short* whp0 = (unsigned short*)take(524288);
    unsigned short* wdp0 = (unsigned short*)take(131072);
    unsigned short* wxp1 = (unsigned short*)take(524288);
    unsigned short* whp1 = (unsigned short*)take(524288);
    unsigned short* wdp1 = (unsigned short*)take(131072);
    float* dec0 = (float*)take(524288);
    float* dec1 = (float*)take(524288);
    unsigned short* hs0 = (unsigned short*)take(131072);
    float* cs0 = (float*)take(262144);
    unsigned short* hs1 = (unsigned short*)take(131072);
    float* cs1 = (float*)take(262144);
    unsigned short* y0bf = (unsigned short*)take(67108864);
    unsigned short* xgpA = (unsigned short*)take(16777216);
    unsigned short* xgpB = (unsigned short*)take(16777216);

    const size_t smem_rec = 147456;  // 128K stage + 8K hb + 8K cb
    hipFuncSetAttribute(reinterpret_cast<const void*>(&rec_fused),
                        hipFuncAttributeMaxDynamicSharedMemorySize, (int)smem_rec);
    hipFuncSetAttribute(reinterpret_cast<const void*>(&gemm_dual),
                        hipFuncAttributeMaxDynamicSharedMemorySize, 65536);

    prep_w<<<128, 256, 0, stream>>>(Wx0, wxp0, 64);
    prep_w<<<128, 256, 0, stream>>>(Wh0, whp0, 64);
    prep_w<<<32, 256, 0, stream>>>(Wd0, wdp0, 16);
    prep_w<<<128, 256, 0, stream>>>(Wx1, wxp1, 64);
    prep_w<<<128, 256, 0, stream>>>(Wh1, whp1, 64);
    prep_w<<<32, 256, 0, stream>>>(Wd1, wdp1, 16);
    prep_decay<<<512, 256, 0, stream>>>(x, dec0, B_ * S_);

    float* y1 = (float*)d_out;
    for (int s = 0; s <= NCHUNK; ++s) {
        int c0 = (s < NCHUNK) ? s : -1;
        int c1 = (s >= 1) ? s - 1 : -1;
        gemm_dual<<<dim3(64, 8, 2), 256, 65536, stream>>>(x, y0bf, wxp0, b0, wxp1, b1,
                                                          xgpA, xgpB, c0, c1);
        rec_fused<<<32, 1024, smem_rec, stream>>>(xgpA, whp0, wdp0, bd0, dec0, y0bf, dec1,
                                                  hs0, cs0, xgpB, whp1, wdp1, bd1, y1,
                                                  hs1, cs1, c0, c1);
    }
    copy_tail<<<1024, 256, 0, stream>>>(hs0, cs0, hs1, cs1, y1 + (size_t)B_ * S_ * H_);
}